// Round 2
// baseline (81.314 us; speedup 1.0000x reference)
//
#include <hip/hip_runtime.h>

// out[b,s,j, r*512 + c*8 + g] = c_s[b,s, j*64+c] * g_s[b,s, r*8+g]
// B=8, S=512, D_C=512, D_G=64, N=8, K_C=64, K_G=8
// Output elements: 8*512*8*4096 = 134,217,728 fp32 (512 MiB) -> write-bound.

#define DC 512
#define DG 64

typedef float f32x4 __attribute__((ext_vector_type(4)));

__global__ __launch_bounds__(256) void OosSlidingWindow_kernel(
    const float* __restrict__ c_s,
    const float* __restrict__ g_s,
    f32x4* __restrict__ out)
{
    // One float4 of output per thread.
    // t = bs*8192 + j*1024 + r*128 + c*2 + g4   (in float4 units)
    unsigned int t = blockIdx.x * blockDim.x + threadIdx.x;

    unsigned int g4 = t & 1u;          // which half of the 8-wide g group
    unsigned int c  = (t >> 1) & 63u;  // position within c-window
    unsigned int r  = (t >> 7) & 7u;   // g-window index
    unsigned int j  = (t >> 10) & 7u;  // c-window index
    unsigned int bs = t >> 13;         // b*512 + s  (0..4095)

    float cv = c_s[bs * DC + j * 64u + c];
    f32x4 gv = *reinterpret_cast<const f32x4*>(&g_s[bs * DG + r * 8u + g4 * 4u]);

    f32x4 o = cv * gv;

    // Output is never re-read: stream it past L2.
    __builtin_nontemporal_store(o, &out[t]);
}

extern "C" void kernel_launch(void* const* d_in, const int* in_sizes, int n_in,
                              void* d_out, int out_size, void* d_ws, size_t ws_size,
                              hipStream_t stream)
{
    const float* c_s = (const float*)d_in[0];
    const float* g_s = (const float*)d_in[1];
    f32x4* out = (f32x4*)d_out;

    // total float4s = 134,217,728 / 4 = 33,554,432 ; blocks = 131,072
    unsigned int n4 = (unsigned int)(out_size / 4);
    unsigned int blocks = n4 / 256u;
    OosSlidingWindow_kernel<<<blocks, 256, 0, stream>>>(c_s, g_s, out);
}